// Round 4
// baseline (108.293 us; speedup 1.0000x reference)
//
#include <hip/hip_runtime.h>

#define T_LEN 256
#define N_LAYERS 128

typedef float f2 __attribute__((ext_vector_type(2)));

// exp2/rcp raw hardware ops, applied per component of a pair.
__device__ __forceinline__ float ex2(float x) { return __builtin_amdgcn_exp2f(x); }
__device__ __forceinline__ float rcpf_(float x) { return __builtin_amdgcn_rcpf(x); }
__device__ __forceinline__ f2 pk_fma(f2 a, f2 b, f2 c) { return __builtin_elementwise_fma(a, b, c); }

// wave_shr:1 (0x138): lane i <- lane i-1 (lane 0 keeps own). VALU pipe.
__device__ __forceinline__ float dpp_wave_shr1(float v) {
    int i = __float_as_int(v);
    return __int_as_float(__builtin_amdgcn_update_dpp(i, i, 0x138, 0xF, 0xF, false));
}
// wave_rol:1 (0x134): lane i <- lane (i+1)%64. x-conveyor toward lane 0.
__device__ __forceinline__ float dpp_wave_rol1(float v) {
    int i = __float_as_int(v);
    return __int_as_float(__builtin_amdgcn_update_dpp(i, i, 0x134, 0xF, 0xF, false));
}

// One wave, 64 lanes, 2 layers/lane, SOFTWARE-PIPELINED wavefront:
// cell (layer l, time t) runs at step s = t + l. Lane i at step s computes
//   cell A = layer 2i   at tA = s - 2i   (input: lane i-1's hB from step s-1, via DPP)
//   cell B = layer 2i+1 at tB = tA - 1   (input: own hA from step s-1)
// => A and B are independent within a step (chain = ONE cell) and execute as
//    packed f32 pairs (v_pk_fma_f32). No LDS anywhere; x reaches lane 0 via a
//    wave_rol:1 register conveyor refilled from 4 preloaded chunks per 64 steps.
// h-updates are cndmask-gated on t-validity (exact ramp in/out).
__global__ __launch_bounds__(64, 1) void gru_stack_wavefront(
    const float* __restrict__ x,
    const float* __restrict__ w_ih,
    const float* __restrict__ w_hh,
    const float* __restrict__ b_ih,
    const float* __restrict__ b_hh,
    float* __restrict__ out)
{
    const int lane = threadIdx.x;  // 0..63
    const int la = 2 * lane, lb = 2 * lane + 1;
    const float L1 = -1.4426950408889634f;   // -log2(e)   (sigmoid scale)
    const float L2 = -2.8853900817779268f;   // -2*log2(e) (tanh scale)

    // Packed per-layer-pair params (x = layer A = 2*lane, y = layer B = 2*lane+1)
    f2 wi_r = { L1 * w_ih[3 * la + 0], L1 * w_ih[3 * lb + 0] };
    f2 wi_z = { L1 * w_ih[3 * la + 1], L1 * w_ih[3 * lb + 1] };
    f2 wi_n = { L2 * w_ih[3 * la + 2], L2 * w_ih[3 * lb + 2] };
    f2 wh_r = { L1 * w_hh[3 * la + 0], L1 * w_hh[3 * lb + 0] };
    f2 wh_z = { L1 * w_hh[3 * la + 1], L1 * w_hh[3 * lb + 1] };
    f2 wh_n = { L2 * w_hh[3 * la + 2], L2 * w_hh[3 * lb + 2] };
    f2 b_r  = { L1 * (b_ih[3 * la + 0] + b_hh[3 * la + 0]),
                L1 * (b_ih[3 * lb + 0] + b_hh[3 * lb + 0]) };
    f2 b_z  = { L1 * (b_ih[3 * la + 1] + b_hh[3 * la + 1]),
                L1 * (b_ih[3 * lb + 1] + b_hh[3 * lb + 1]) };
    f2 bi_n = { L2 * b_ih[3 * la + 2], L2 * b_ih[3 * lb + 2] };
    f2 bh_n = { L2 * b_hh[3 * la + 2], L2 * b_hh[3 * lb + 2] };

    // x conveyor chunks: lane holds x[lane + 64k]
    float xc0 = x[lane];
    float xc1 = x[lane + 64];
    float xc2 = x[lane + 128];
    float xc3 = x[lane + 192];

    f2 h = { 0.0f, 0.0f };           // {hA, hB}
    // h-dependent pre-activations (exp2-scaled), computed off the input chain
    f2 c_r = b_r, c_z = b_z, g_n = bh_n;

    const f2 one2 = { 1.0f, 1.0f };
    const f2 two2 = { 2.0f, 2.0f };
    const f2 mone2 = { -1.0f, -1.0f };

    const bool is_l0 = (lane == 0);
    int tA = -2 * lane - 1;          // incremented at top of each step -> tA = s - 2*lane

    for (int blk = 0; blk < 6; ++blk) {
        float xq;
        if      (blk == 0) xq = xc0;
        else if (blk == 1) xq = xc1;
        else if (blk == 2) xq = xc2;
        else               xq = xc3;   // blocks 4,5: garbage, fully gated off

        #pragma unroll 8
        for (int k = 0; k < 64; ++k) {
            ++tA;
            const bool validA = (unsigned)tA < (unsigned)T_LEN;
            const bool validB = (unsigned)(tA - 1) < (unsigned)T_LEN;

            // cell A input: neighbor's hB from last step (DPP); lane 0: x[s]
            float shifted = dpp_wave_shr1(h.y);
            float inA = is_l0 ? xq : shifted;
            f2 in2 = { inA, h.x };    // cell B input: own hA from last step

            // gates r, z (sigmoid), n (tanh) — packed where possible
            f2 u_r = pk_fma(wi_r, in2, c_r);
            f2 u_z = pk_fma(wi_z, in2, c_z);
            f2 u_n0 = pk_fma(wi_n, in2, bi_n);
            f2 e_r = { ex2(u_r.x), ex2(u_r.y) };
            f2 e_z = { ex2(u_z.x), ex2(u_z.y) };
            f2 d_r = e_r + one2;
            f2 d_z = e_z + one2;
            f2 r2 = { rcpf_(d_r.x), rcpf_(d_r.y) };
            f2 z2 = { rcpf_(d_z.x), rcpf_(d_z.y) };
            f2 u_n = pk_fma(r2, g_n, u_n0);
            f2 e_n = { ex2(u_n.x), ex2(u_n.y) };
            f2 d_n = e_n + one2;
            f2 s_n = { rcpf_(d_n.x), rcpf_(d_n.y) };
            f2 n2 = pk_fma(two2, s_n, mone2);          // tanh = 2*sig(2v)-1
            f2 hn = pk_fma(z2, h - n2, n2);            // (1-z)*n + z*h

            h.x = validA ? hn.x : h.x;
            h.y = validB ? hn.y : h.y;

            // precomputes for next step (off the input-critical chain)
            c_r = pk_fma(wh_r, h, b_r);
            c_z = pk_fma(wh_z, h, b_z);
            g_n = pk_fma(wh_n, h, bh_n);

            if (lane == 63 && validB) out[tA - 1] = h.y;   // layer 127 output

            xq = dpp_wave_rol1(xq);   // conveyor: lane 0 sees x[s+1] next step
        }
    }
}

extern "C" void kernel_launch(void* const* d_in, const int* in_sizes, int n_in,
                              void* d_out, int out_size, void* d_ws, size_t ws_size,
                              hipStream_t stream) {
    const float* x    = (const float*)d_in[0];  // [1,256]
    const float* w_ih = (const float*)d_in[1];  // [128,3,1]
    const float* w_hh = (const float*)d_in[2];  // [128,3,1]
    const float* b_ih = (const float*)d_in[3];  // [128,3]
    const float* b_hh = (const float*)d_in[4];  // [128,3]
    float* out = (float*)d_out;                 // [1,256]

    gru_stack_wavefront<<<1, 64, 0, stream>>>(x, w_ih, w_hh, b_ih, b_hh, out);
}